// Round 5
// baseline (187.983 us; speedup 1.0000x reference)
//
#include <hip/hip_runtime.h>

// Scaled dot-product attention, B=2 H=12 S=2048 D=64, fp32 in/out.
// Outputs: out [B,H,S,D] then we [B,H,S,S] concatenated in d_out.
// Two-pass: pass1 row sums of exp(QK^T/8 + mask); pass2 recompute,
// write normalized we (f32x4, coalesced via S^T layout), PV via MFMA.
// R4 = R3 with the nontemporal-store operand as clang ext_vector f32x4
// (HIP float4 is a class type the builtin rejects).

typedef short          s16x8 __attribute__((ext_vector_type(8)));
typedef unsigned short u16x8 __attribute__((ext_vector_type(8)));
typedef unsigned short u16x4 __attribute__((ext_vector_type(4)));
typedef float          f32x4 __attribute__((ext_vector_type(4)));

#define kS   2048
#define kD   64
#define kBH  24
#define OUT_ELEMS (kBH * kS * kD)   // 3145728

static __device__ __forceinline__ unsigned short f2bf(float f) {
    union { float f; unsigned u; } x; x.f = f;
    return (unsigned short)((x.u + 0x7fffu + ((x.u >> 16) & 1u)) >> 16); // RNE
}

static __device__ __forceinline__ u16x8 cvt8(const float4 f0, const float4 f1) {
    u16x8 r;
    r[0] = f2bf(f0.x); r[1] = f2bf(f0.y); r[2] = f2bf(f0.z); r[3] = f2bf(f0.w);
    r[4] = f2bf(f1.x); r[5] = f2bf(f1.y); r[6] = f2bf(f1.z); r[7] = f2bf(f1.w);
    return r;
}

__global__ __launch_bounds__(256)
void attn_fused(const float* __restrict__ Qg, const float* __restrict__ Kg,
                const float* __restrict__ Vg, const float* __restrict__ Mg,
                float* __restrict__ Og, float* __restrict__ Wg)
{
    // K tile [32 t][64 d] bf16, XOR-swizzled: byte ^= (row&7)<<4  (x2 dbuf)
    __shared__ __align__(16) unsigned short k_sh[2][32 * 64];
    // V^T tile [64 d][32 t] bf16, XOR-swizzled: byte ^= ((d>>3)&7)<<4 (x2 dbuf)
    __shared__ __align__(16) unsigned short vt_sh[2][64 * 32];
    // per-wave P tile [16 q][40 t-pad] bf16
    __shared__ __align__(16) unsigned short p_sh[4][16 * 40];

    const int tid  = threadIdx.x;
    const int wv   = tid >> 6;
    const int lane = tid & 63;
    const int g    = lane >> 4;   // 0..3
    const int c    = lane & 15;   // 0..15

    // XCD-bijective swizzle: 768 blocks, 96/XCD => each XCD owns 3 whole heads
    const int wg = ((int)blockIdx.x & 7) * 96 + ((int)blockIdx.x >> 3);
    const int bh = wg >> 5;
    const int qb = wg & 31;
    const int q0 = qb * 64 + wv * 16;

    // Q fragment (row q0+c, d = h*32 + g*8 + j) — B-operand of swapped QK^T
    s16x8 aQ[2];
    {
        const float* qp = Qg + ((size_t)(bh * kS + q0 + c)) * kD + g * 8;
        #pragma unroll
        for (int h = 0; h < 2; ++h) {
            float4 f0 = *(const float4*)(qp + h * 32);
            float4 f1 = *(const float4*)(qp + h * 32 + 4);
            union { u16x8 u; s16x8 s; } t; t.u = cvt8(f0, f1);
            aQ[h] = t.s;
        }
    }

    // staging: thread -> (row sr, cols sc..sc+7) of the 32x64 fp32 tile
    const int sr = tid >> 3;          // 0..31
    const int sc = (tid & 7) * 8;     // 0..56
    const float* kstage = Kg + ((size_t)bh * kS + sr) * kD + sc;
    const float* vstage = Vg + ((size_t)bh * kS + sr) * kD + sc;
    const unsigned kaddr_w = (unsigned)((sr * 128 + sc * 2) ^ ((sr & 7) << 4));
    const float* mrow = Mg + (size_t)(q0 + c) * kS;   // this lane's mask row (q = q0+c)

    // ================= pass 1: softmax denominators =================
    {
        const float* src = kstage;
        *(u16x8*)((char*)k_sh[0] + kaddr_w) = cvt8(*(const float4*)src, *(const float4*)(src + 4));
    }
    __syncthreads();

    float sm = 0.f;
    int cur = 0;
    for (int t0 = 0; t0 < kS; t0 += 32) {
        const bool nxt = (t0 + 32) < kS;
        float4 kf0, kf1;
        if (nxt) {   // issue-early prefetch of next tile (hidden under compute)
            const float* src = kstage + (size_t)(t0 + 32) * kD;
            kf0 = *(const float4*)src; kf1 = *(const float4*)(src + 4);
        }
        #pragma unroll
        for (int tt = 0; tt < 2; ++tt) {
            const int row = tt * 16 + c;
            f32x4 acc = {0.f, 0.f, 0.f, 0.f};
            #pragma unroll
            for (int h = 0; h < 2; ++h) {
                const unsigned a = (unsigned)((row * 128 + h * 64 + g * 16) ^ ((row & 7) << 4));
                s16x8 bK = *(const s16x8*)((const char*)k_sh[cur] + a);
                // swapped: D = K_tile · Q^T = S^T ; lane (g,c): rows t, col q0+c
                acc = __builtin_amdgcn_mfma_f32_16x16x32_bf16(bK, aQ[h], acc, 0, 0, 0);
            }
            const float4 mk = *(const float4*)(mrow + t0 + tt * 16 + g * 4);
            sm += __expf(acc[0] * 0.125f + mk.x);
            sm += __expf(acc[1] * 0.125f + mk.y);
            sm += __expf(acc[2] * 0.125f + mk.z);
            sm += __expf(acc[3] * 0.125f + mk.w);
        }
        if (nxt) {
            *(u16x8*)((char*)k_sh[cur ^ 1] + kaddr_w) = cvt8(kf0, kf1);
            __syncthreads();
            cur ^= 1;
        }
    }
    // reduce over the 4 g-groups holding the same q=c
    sm += __shfl_xor(sm, 16);
    sm += __shfl_xor(sm, 32);
    const float sminv = 1.0f / sm;

    // ================= pass 2: write we, accumulate PV =================
    f32x4 accO[4];
    #pragma unroll
    for (int dt = 0; dt < 4; ++dt) accO[dt] = f32x4{0.f, 0.f, 0.f, 0.f};

    float* wrow = Wg + ((size_t)(bh * kS + q0 + c)) * kS;   // we row q0+c

    __syncthreads();   // pass1 LDS reads complete before restaging buf0
    {
        const float* srck = kstage;
        *(u16x8*)((char*)k_sh[0] + kaddr_w) = cvt8(*(const float4*)srck, *(const float4*)(srck + 4));
        const float* srcv = vstage;
        u16x8 vb = cvt8(*(const float4*)srcv, *(const float4*)(srcv + 4));
        #pragma unroll
        for (int i = 0; i < 8; ++i) {
            const int d = sc + i;
            const unsigned b = (unsigned)((d * 64 + sr * 2) ^ (((d >> 3) & 7) << 4));
            *(unsigned short*)((char*)vt_sh[0] + b) = vb[i];
        }
    }
    __syncthreads();

    cur = 0;
    for (int t0 = 0; t0 < kS; t0 += 32) {
        const bool nxt = (t0 + 32) < kS;
        float4 kf0, kf1, vf0, vf1;
        if (nxt) {
            const float* srck = kstage + (size_t)(t0 + 32) * kD;
            kf0 = *(const float4*)srck; kf1 = *(const float4*)(srck + 4);
            const float* srcv = vstage + (size_t)(t0 + 32) * kD;
            vf0 = *(const float4*)srcv; vf1 = *(const float4*)(srcv + 4);
        }

        #pragma unroll
        for (int tt = 0; tt < 2; ++tt) {
            const int row = tt * 16 + c;
            f32x4 acc = {0.f, 0.f, 0.f, 0.f};
            #pragma unroll
            for (int h = 0; h < 2; ++h) {
                const unsigned a = (unsigned)((row * 128 + h * 64 + g * 16) ^ ((row & 7) << 4));
                s16x8 bK = *(const s16x8*)((const char*)k_sh[cur] + a);
                acc = __builtin_amdgcn_mfma_f32_16x16x32_bf16(bK, aQ[h], acc, 0, 0, 0);
            }
            const float4 mk = *(const float4*)(mrow + t0 + tt * 16 + g * 4);
            f32x4 p;
            p[0] = __expf(acc[0] * 0.125f + mk.x) * sminv;
            p[1] = __expf(acc[1] * 0.125f + mk.y) * sminv;
            p[2] = __expf(acc[2] * 0.125f + mk.z) * sminv;
            p[3] = __expf(acc[3] * 0.125f + mk.w) * sminv;
            // lane holds we[q0+c][t0+tt*16+g*4 .. +3] -> coalesced 16B store
            __builtin_nontemporal_store(p, (f32x4*)(wrow + t0 + tt * 16 + g * 4));
            u16x4 pb;
            pb[0] = f2bf(p[0]); pb[1] = f2bf(p[1]); pb[2] = f2bf(p[2]); pb[3] = f2bf(p[3]);
            *(u16x4*)&p_sh[wv][c * 40 + tt * 16 + g * 4] = pb;
        }

        // A-frag of P: row=c, k=g*8+j (same as verified R2 read)
        s16x8 pa = *(const s16x8*)((const char*)&p_sh[wv][0] + c * 80 + g * 16);
        #pragma unroll
        for (int dt = 0; dt < 4; ++dt) {
            const int d = dt * 16 + c;
            const unsigned b = (unsigned)((d * 64 + g * 16) ^ (((d >> 3) & 7) << 4));
            s16x8 bV = *(const s16x8*)((const char*)vt_sh[cur] + b);
            accO[dt] = __builtin_amdgcn_mfma_f32_16x16x32_bf16(pa, bV, accO[dt], 0, 0, 0);
        }

        if (nxt) {
            *(u16x8*)((char*)k_sh[cur ^ 1] + kaddr_w) = cvt8(kf0, kf1);
            u16x8 vb = cvt8(vf0, vf1);
            #pragma unroll
            for (int i = 0; i < 8; ++i) {
                const int d = sc + i;
                const unsigned b = (unsigned)((d * 64 + sr * 2) ^ (((d >> 3) & 7) << 4));
                *(unsigned short*)((char*)vt_sh[cur ^ 1] + b) = vb[i];
            }
            __syncthreads();
            cur ^= 1;
        }
    }

    // ---- epilogue: out[bh][q0+g*4+j][dt*16+c] (unchanged from R2) ----
    float* orow = Og + ((size_t)(bh * kS + q0 + g * 4)) * kD + c;
    #pragma unroll
    for (int dt = 0; dt < 4; ++dt) {
        #pragma unroll
        for (int j = 0; j < 4; ++j)
            __builtin_nontemporal_store(accO[dt][j], orow + (size_t)j * kD + dt * 16);
    }
}

extern "C" void kernel_launch(void* const* d_in, const int* in_sizes, int n_in,
                              void* d_out, int out_size, void* d_ws, size_t ws_size,
                              hipStream_t stream) {
    const float* q = (const float*)d_in[0];
    const float* k = (const float*)d_in[1];
    const float* v = (const float*)d_in[2];
    const float* m = (const float*)d_in[3];
    float* out = (float*)d_out;
    float* we  = out + OUT_ELEMS;
    attn_fused<<<dim3(kBH * 32), dim3(256), 0, stream>>>(q, k, v, m, out, we);
}